// Round 15
// baseline (599.647 us; speedup 1.0000x reference)
//
#include <hip/hip_runtime.h>
#include <hip/hip_bf16.h>
#include <stdint.h>

// MutualCrossAttention: B=8, C=64, H=W=64 -> T=4096 tokens. Inputs FP32, output FP32.
// dir A: Q=x1, K=V=x2 ; dir B: Q=x2, K=V=x1 ; out = outA + outB, layout [b][c][t].
// R27 = R26 (1024-thread 16-wave block, parity pbuf, single K + single V
// prefetch sets) + __launch_bounds__(1024, 2). R26 split the verdict cleanly:
//   - CP side PROVED: 1024-thr block forced 16 waves/CU (Occupancy 45.9% after
//     13 rounds stuck at 22%). Blocks are atomic -> residency loophole works.
//   - Compiler side broke: with no waves-per-EU declaration the allocator
//     reverted to the 64-reg tier and spilled ~132 regs of demand (WRITE
//     1.75GB). The R16-18 law: budget = 256/declared_min_waves_per_EU.
// Declaring min=2 -> budget 128 = exactly the physical max for a 16-wave CU
// (512 VGPR/SIMD / 4 waves). Demand (~132: kA 32 + vA 32 + qf 16 + accO 32 +
// addr) fits with minor shaving. min=2 is trivially satisfied (block gives 4).
// Everything else identical to R26:
//   Per j-pair: S(j)->par0 | loadK(j+1) | PV(j-1)<-par1 | loadV(j) |
//               S(j+1)->par1 | loadK(j+2) | PV(j)<-par0 | loadV(j+1)
//   (barrier-free; parity pbuf gives every load/pbuf-hop >=1 sub-phase cover)
//   Waves = (dir, pair, ks, qt_sub); grid 256 = 1 block/CU exactly.
//   LDS: pbuf[16][2][2][16][72] = 144KB + lpx 2KB = 146KB <= 160.
//   kt chunk(tt,mt,ch):  lane(quad,l16) holds K[t=tt*64+mt*16+l16][c=ch*32+quad*8+e]
//   vt chunk(tt,ch2,ct): lane(quad,l16) holds V[c=ct*16+l16][t=tt*64+ch2*32+quad*8+e]
//   Q frags are kt chunks at (qt, mt=pair*2+rb, ch) — all hot loads 1KB/instr.
//   S^T composition (A=K,B=Q then A=V,B=P^T); P^T C/D -> b64 write, b128 read.
//   lp scalar/lane; ks-partner = wave^4 via lpx; 4-phase merge per (qsub,pair).
// ws: [0,8MB) kt bf16 frag-packed {x1,x2} PRE-SCALED by sqrt(log2(e)/8);
//     [8MB,16MB) vt bf16 frag-packed {x1,x2} unscaled.

#define TT 4096
#define CC 64
#define NB 8

typedef float f32x4 __attribute__((ext_vector_type(4)));
typedef float f32x4a __attribute__((ext_vector_type(4), may_alias));
typedef short s16x8 __attribute__((ext_vector_type(8)));
typedef unsigned int u32x2a __attribute__((ext_vector_type(2), may_alias));
typedef unsigned int u32x4a __attribute__((ext_vector_type(4), may_alias));
typedef float f32a __attribute__((may_alias));

static __device__ __forceinline__ unsigned fbits(float x) { return __float_as_uint(x); }
static __device__ __forceinline__ ushort bf16of(float v) {
    return (ushort)((fbits(v) + 0x8000u) >> 16);
}
static __device__ __forceinline__ unsigned pack2(float a, float b) {
    return __builtin_amdgcn_perm(fbits(b) + 0x8000u, fbits(a) + 0x8000u, 0x07060302u);
}
static __device__ __forceinline__ s16x8 load_frag(const void* p) {
    u32x4a t = *(const u32x4a*)p;
    return __builtin_bit_cast(s16x8, t);
}

#define SQC1 0.4246609177f  // sqrt(log2(e)/8), applied to kt on both Q and K sides

// grid (TT/64, NB, 2), 256 threads. Reads c-major f32, emits frag-packed bf16.
__global__ void prep_k(const float* __restrict__ x1, const float* __restrict__ x2,
                       ushort* __restrict__ kt, ushort* __restrict__ vt) {
    const int inp = blockIdx.z, b = blockIdx.y, tt = blockIdx.x;
    const float* src = (inp == 0 ? x1 : x2) + (size_t)b * CC * TT;
    const size_t plane = (size_t)TT * CC;
    ushort* kd = kt + (size_t)(inp * NB + b) * plane;
    ushort* vd = vt + (size_t)(inp * NB + b) * plane;
    __shared__ ushort lds[64][72];
    const int tid = threadIdx.x;
    const int c  = tid >> 2;        // 0..63: channel row
    const int tg = tid & 3;         // 16-token group within the 64-token tile
    const float* srow = src + (size_t)c * TT + tt * 64 + tg * 16;
    unsigned hw[8];
#pragma unroll
    for (int i = 0; i < 4; ++i) {
        f32x4a v = *(const f32x4a*)(srow + i * 4);
        hw[2 * i]     = pack2(v[0], v[1]);
        hw[2 * i + 1] = pack2(v[2], v[3]);
#pragma unroll
        for (int k = 0; k < 4; ++k) lds[tg * 16 + i * 4 + k][c] = bf16of(v[k] * SQC1);
    }
    // vt frag-packed (unscaled): thread(c,tg) owns V[c][t_local=tg*16..+16] =
    // chunk(tt, ch2=tg>>1, ct=c>>4), lanes (quad=(tg&1)*2 and +1, l16=c&15).
    {
        ushort* vchunk = vd + (((size_t)tt * 2 + (tg >> 1)) * 4 + (c >> 4)) * 512;
        const int l16v = c & 15;
        const int q0v  = (tg & 1) * 2;
        u32x4a w0 = {hw[0], hw[1], hw[2], hw[3]};
        u32x4a w1 = {hw[4], hw[5], hw[6], hw[7]};
        *(u32x4a*)(vchunk + (size_t)(q0v * 16 + l16v) * 8)       = w0;
        *(u32x4a*)(vchunk + (size_t)((q0v + 1) * 16 + l16v) * 8) = w1;
    }
    __syncthreads();
    // kt frag-packed (scaled, from transposed LDS): tid = mt*64 + quad*16 + l16.
    // chunk(tt, mt, ch): lane holds 8 consecutive c at row t = mt*16 + l16.
    const int mt   = tid >> 6;
    const int quad = (tid >> 4) & 3;
    const int l16  = tid & 15;
    const int t    = mt * 16 + l16;
#pragma unroll
    for (int ch = 0; ch < 2; ++ch) {
        u32x4a w = *(const u32x4a*)&lds[t][ch * 32 + quad * 8];
        *(u32x4a*)(kd + (((size_t)tt * 4 + mt) * 2 + ch) * 512 +
                   (size_t)(quad * 16 + l16) * 8) = w;
    }
}

// grid = 256 blocks (qt2 0..31 x b 0..7), 1024 threads = 16 waves.
// wave: dir = w&1, pair = (w>>1)&1, ks = (w>>2)&1, qt_sub = w>>3.
// launch_bounds(1024, 2): min-waves 2 -> VGPR budget 256/2 = 128 = physical
// max for 4 waves/SIMD. Block residency forces 16 waves/CU (R26-proved).
__global__ __launch_bounds__(1024, 2)
void attn_fused_k(const ushort* __restrict__ kt, const ushort* __restrict__ vt,
                  float* __restrict__ out) {
    const int b     = blockIdx.x & 7;
    const int qt2   = blockIdx.x >> 3;
    const int tid   = threadIdx.x;
    const int wave  = tid >> 6;
    const int lane  = tid & 63;
    const int quad  = lane >> 4;
    const int l16   = lane & 15;
    const int dir   = wave & 1;
    const int pair  = (wave >> 1) & 1;
    const int ks    = (wave >> 2) & 1;
    const int qsub  = wave >> 3;
    const int qt    = qt2 * 2 + qsub;
    const int q0    = qt * 64 + pair * 32;

    const size_t plane = (size_t)TT * CC;
    // All hot-loop loads: base + chunk*512 + lane*8 (ushorts) = contiguous 1KB/instr.
    const ushort* Qp = kt + (size_t)((dir == 0 ? 0 : NB) + b) * plane + (size_t)lane * 8;
    const ushort* Kp = kt + (size_t)((dir == 0 ? NB : 0) + b) * plane + (size_t)lane * 8;
    const ushort* Vp = vt + (size_t)((dir == 0 ? NB : 0) + b) * plane + (size_t)lane * 8;

    // Parity pbuf: S(j+1) writes and PV(j) reads touch different regions.
    __shared__ __align__(16) ushort pbuf[16][2][2][16][72];  // 144 KB
    __shared__ float lpx[16][2][16];                         // 2 KB
    f32a* xbuf = (f32a*)&pbuf[0][0][0][0][0];                // 32 KB overlay, post-loop

    // Q b-frags = kt chunks (qt, mt = pair*2 + rb, ch), pre-scaled.
    s16x8 qf[2][2];
#pragma unroll
    for (int rb = 0; rb < 2; ++rb)
#pragma unroll
        for (int ch = 0; ch < 2; ++ch)
            qf[rb][ch] = load_frag(Qp + (((size_t)qt * 4 + pair * 2 + rb) * 2 + ch) * 512);

    f32x4 accO[2][4];  // O^T partial: row=c=quad*4+r (+ct*16), col=q=l16 (+rb*16)
#pragma unroll
    for (int rb = 0; rb < 2; ++rb)
#pragma unroll
        for (int ct = 0; ct < 4; ++ct) accO[rb][ct] = (f32x4){0.f, 0.f, 0.f, 0.f};
    float lp[2] = {0.f, 0.f};

    // SINGLE K set + SINGLE V set (named; arrays spill — R14/R15).
    s16x8 kA0, kA1, kA2, kA3, kA4, kA5, kA6, kA7;
    s16x8 vA0, vA1, vA2, vA3, vA4, vA5, vA6, vA7;

    auto loadK = [&](int j) {
        const ushort* p = Kp + (size_t)(ks * 32 + j) * 4096;
        kA0 = load_frag(p);          kA1 = load_frag(p + 512);
        kA2 = load_frag(p + 1024);   kA3 = load_frag(p + 1536);
        kA4 = load_frag(p + 2048);   kA5 = load_frag(p + 2560);
        kA6 = load_frag(p + 3072);   kA7 = load_frag(p + 3584);
    };
    auto loadV = [&](int j) {
        const ushort* p = Vp + (size_t)(ks * 32 + j) * 4096;
        vA0 = load_frag(p);          vA1 = load_frag(p + 512);
        vA2 = load_frag(p + 1024);   vA3 = load_frag(p + 1536);
        vA4 = load_frag(p + 2048);   vA5 = load_frag(p + 2560);
        vA6 = load_frag(p + 3072);   vA7 = load_frag(p + 3584);
    };

    // One mt-slice of S^T into parity region par:
    // D[row=tok=quad*4+r (+mt*16)][col=q=l16] -> b64 P write.
    auto SmT = [&](int mt, int par) {
        s16x8 kc0, kc1;
        if (mt == 0)      { kc0 = kA0; kc1 = kA1; }
        else if (mt == 1) { kc0 = kA2; kc1 = kA3; }
        else if (mt == 2) { kc0 = kA4; kc1 = kA5; }
        else              { kc0 = kA6; kc1 = kA7; }
#pragma unroll
        for (int rb = 0; rb < 2; ++rb) {
            f32x4 s = (f32x4){0.f, 0.f, 0.f, 0.f};
            s = __builtin_amdgcn_mfma_f32_16x16x32_bf16(kc0, qf[rb][0], s, 0, 0, 0);
            s = __builtin_amdgcn_mfma_f32_16x16x32_bf16(kc1, qf[rb][1], s, 0, 0, 0);
            float p0 = __builtin_amdgcn_exp2f(s[0]);
            float p1 = __builtin_amdgcn_exp2f(s[1]);
            float p2 = __builtin_amdgcn_exp2f(s[2]);
            float p3 = __builtin_amdgcn_exp2f(s[3]);
            lp[rb] += (p0 + p1) + (p2 + p3);
            u32x2a w;
            w[0] = pack2(p0, p1);
            w[1] = pack2(p2, p3);
            *(u32x2a*)&pbuf[wave][par][rb][l16][mt * 16 + quad * 4] = w;
        }
    };
    auto Sphase = [&](int par) { SmT(0, par); SmT(1, par); SmT(2, par); SmT(3, par); };

    // PV from parity region par with the (single) V set.
    auto PVphase = [&](int par) {
        s16x8 pf0a = load_frag(&pbuf[wave][par][0][l16][quad * 8]);
        s16x8 pf1a = load_frag(&pbuf[wave][par][1][l16][quad * 8]);
        accO[0][0] = __builtin_amdgcn_mfma_f32_16x16x32_bf16(vA0, pf0a, accO[0][0], 0, 0, 0);
        accO[1][0] = __builtin_amdgcn_mfma_f32_16x16x32_bf16(vA0, pf1a, accO[1][0], 0, 0, 0);
        accO[0][1] = __builtin_amdgcn_mfma_f32_16x16x32_bf16(vA1, pf0a, accO[0][1], 0, 0, 0);
        accO[1][1] = __builtin_amdgcn_mfma_f32_16x16x32_bf16(vA1, pf1a, accO[1][1], 0, 0, 0);
        accO[0][2] = __builtin_amdgcn_mfma_f32_16x16x32_bf16(vA2, pf0a, accO[0][2], 0, 0, 0);
        accO[1][2] = __builtin_amdgcn_mfma_f32_16x16x32_bf16(vA2, pf1a, accO[1][2], 0, 0, 0);
        accO[0][3] = __builtin_amdgcn_mfma_f32_16x16x32_bf16(vA3, pf0a, accO[0][3], 0, 0, 0);
        accO[1][3] = __builtin_amdgcn_mfma_f32_16x16x32_bf16(vA3, pf1a, accO[1][3], 0, 0, 0);
        s16x8 pf0b = load_frag(&pbuf[wave][par][0][l16][32 + quad * 8]);
        s16x8 pf1b = load_frag(&pbuf[wave][par][1][l16][32 + quad * 8]);
        accO[0][0] = __builtin_amdgcn_mfma_f32_16x16x32_bf16(vA4, pf0b, accO[0][0], 0, 0, 0);
        accO[1][0] = __builtin_amdgcn_mfma_f32_16x16x32_bf16(vA4, pf1b, accO[1][0], 0, 0, 0);
        accO[0][1] = __builtin_amdgcn_mfma_f32_16x16x32_bf16(vA5, pf0b, accO[0][1], 0, 0, 0);
        accO[1][1] = __builtin_amdgcn_mfma_f32_16x16x32_bf16(vA5, pf1b, accO[1][1], 0, 0, 0);
        accO[0][2] = __builtin_amdgcn_mfma_f32_16x16x32_bf16(vA6, pf0b, accO[0][2], 0, 0, 0);
        accO[1][2] = __builtin_amdgcn_mfma_f32_16x16x32_bf16(vA6, pf1b, accO[1][2], 0, 0, 0);
        accO[0][3] = __builtin_amdgcn_mfma_f32_16x16x32_bf16(vA7, pf0b, accO[0][3], 0, 0, 0);
        accO[1][3] = __builtin_amdgcn_mfma_f32_16x16x32_bf16(vA7, pf1b, accO[1][3], 0, 0, 0);
    };

    // Barrier-free parity pipeline. Per j-pair (j even):
    //   S(j)->par0 | loadK(j+1) | PV(j-1)<-par1 | loadV(j) |
    //   S(j+1)->par1 | loadK(j+2) | PV(j)<-par0 | loadV(j+1)
    // Every load has >= 1 sub-phase (~400cy) of cover; all WAR hazards resolve
    // in program order (loads issue after their register's last consumer).
    loadK(0);
#pragma unroll 1
    for (int j = 0; j < 32; j += 2) {
        Sphase(0);                       // S(j), uses K(j)
        loadK(j + 1);
        if (j > 0) PVphase(1);           // PV(j-1), uses V(j-1)
        loadV(j);
        Sphase(1);                       // S(j+1), uses K(j+1)
        if (j + 2 < 32) loadK(j + 2);
        PVphase(0);                      // PV(j), uses V(j)
        loadV(j + 1);
    }
    PVphase(1);                          // PV(31), uses V(31)

    // Denominator: quads hold disjoint token subsets for col q=l16.
    float inv[2];
#pragma unroll
    for (int rb = 0; rb < 2; ++rb) {
        float l = lp[rb];
        l += __shfl_xor(l, 16);
        l += __shfl_xor(l, 32);
        lp[rb] = l;
        if (lane < 16) lpx[wave][rb][l16] = l;
    }
    __syncthreads();  // joins ALL 16 waves after their last pbuf use ->
                      // xbuf overlay safe; lpx visible
#pragma unroll
    for (int rb = 0; rb < 2; ++rb)
        inv[rb] = __builtin_amdgcn_rcpf(lp[rb] + lpx[wave ^ 4][rb][l16]);

    // 4-phase merge over g = (ks,dir) within each (qsub,pair) group; g==0 stores.
    const int g = (ks << 1) | dir;
    const int grp = qsub * 2 + pair;
#pragma unroll 1
    for (int ph = 3; ph >= 1; --ph) {
        if (g == ph) {
#pragma unroll
            for (int rb = 0; rb < 2; ++rb)
#pragma unroll
                for (int ct = 0; ct < 4; ++ct)
#pragma unroll
                    for (int r = 0; r < 4; ++r) {
                        const int slot = (grp * 32 + rb * 16 + ct * 4 + r) * 64 + lane;
                        float v = accO[rb][ct][r] * inv[rb];
                        if (ph == 3) xbuf[slot] = v;
                        else xbuf[slot] += v;
                    }
        }
        __syncthreads();
    }
    if (g == 0) {
        float* ob = out + (size_t)b * plane;
#pragma unroll
        for (int rb = 0; rb < 2; ++rb)
#pragma unroll
            for (int ct = 0; ct < 4; ++ct)
#pragma unroll
                for (int r = 0; r < 4; ++r) {
                    float v = accO[rb][ct][r] * inv[rb] +
                              xbuf[(grp * 32 + rb * 16 + ct * 4 + r) * 64 + lane];
                    // out[c = ct*16+quad*4+r][t = q0+rb*16+l16]: coalesced over l16
                    ob[(size_t)(ct * 16 + quad * 4 + r) * TT + q0 + rb * 16 + l16] = v;
                }
    }
}

extern "C" void kernel_launch(void* const* d_in, const int* in_sizes, int n_in,
                              void* d_out, int out_size, void* d_ws, size_t ws_size,
                              hipStream_t stream) {
    const float* x1 = (const float*)d_in[0];
    const float* x2 = (const float*)d_in[1];
    ushort* kt = (ushort*)d_ws;                              // 8 MB frag-packed K/Q
    ushort* vt = (ushort*)d_ws + (size_t)2 * NB * TT * CC;   // 8 MB frag-packed V

    hipLaunchKernelGGL(prep_k, dim3(TT / 64, NB, 2), dim3(256), 0, stream, x1, x2, kt, vt);
    hipLaunchKernelGGL(attn_fused_k, dim3(32 * NB), dim3(1024), 0, stream,
                       kt, vt, (float*)d_out);
}

// Round 16
// 163.512 us; speedup vs baseline: 3.6673x; 3.6673x over previous
//
#include <hip/hip_runtime.h>
#include <hip/hip_bf16.h>
#include <stdint.h>

// MutualCrossAttention: B=8, C=64, H=W=64 -> T=4096 tokens. Inputs FP32, output FP32.
// dir A: Q=x1, K=V=x2 ; dir B: Q=x2, K=V=x1 ; out = outA + outB, layout [b][c][t].
// R28 = R25 (champion: 105us attn / 163.6us total — frag-packed K/V/Q,
// barrier-free counted-vmcnt loop, parity pbuf double-buffer, 4 named prefetch
// sets) with __launch_bounds__(512, 1): budget 256 VGPR instead of 128.
// R25's VGPR came out at EXACTLY 128 (the (512,2) ceiling) -> allocator at its
// cap serializes register reuse across the prefetch sets. Residency cannot
// drop below 1 block (13 rounds: CP never hosts a 2nd 512-thr block at any
// VGPR 64..128; 1024-thr blocks force 16 waves but pin the allocator to the
// 64-reg tier and spill, R26/R27) -> declaring min-waves=1 is residency-free
// and only relaxes the register budget.
// Occupancy ledger (closed): allocator default budgets for 2 blocks/CU
// (512thr->128, 1024thr->64, 256thr->256 regs); CP hosts 1 block regardless.
//   kt chunk(tt,mt,ch):  lane(quad,l16) holds K[t=tt*64+mt*16+l16][c=ch*32+quad*8+e]
//   vt chunk(tt,ch2,ct): lane(quad,l16) holds V[c=ct*16+l16][t=tt*64+ch2*32+quad*8+e]
// Q frags are kt chunks at (qt, mt=pair*2+rb, ch) — all hot loads contiguous 1KB.
//   - Parity pbuf[par=j&1]: S(j+1) writes and PV(j) reads touch different
//     regions -> DS in-order queue no longer serializes them (R25: +13us).
//   - Barrier-free loop (R23: +4us): hipcc force-drains vmcnt before s_barrier;
//     pbuf is wave-private so the loop needs no sync.
//   - S^T composition (A=K,B=Q then A=V,B=P^T): P^T C/D layout gives 4
//     consecutive tokens/lane -> b64 pbuf write, b128 read, stride-72.
//   - lp is one scalar per lane (q = l16 column), butterflied over quads.
//   - O^T epilogue: row=c, col=q -> scalar f32 stores coalesced over l16.
// ws: [0,8MB) kt bf16 frag-packed {x1,x2} PRE-SCALED by sqrt(log2(e)/8);
//     [8MB,16MB) vt bf16 frag-packed {x1,x2} unscaled.

#define TT 4096
#define CC 64
#define NB 8

typedef float f32x4 __attribute__((ext_vector_type(4)));
typedef float f32x4a __attribute__((ext_vector_type(4), may_alias));
typedef short s16x8 __attribute__((ext_vector_type(8)));
typedef unsigned int u32x2a __attribute__((ext_vector_type(2), may_alias));
typedef unsigned int u32x4a __attribute__((ext_vector_type(4), may_alias));
typedef float f32a __attribute__((may_alias));

static __device__ __forceinline__ unsigned fbits(float x) { return __float_as_uint(x); }
static __device__ __forceinline__ ushort bf16of(float v) {
    return (ushort)((fbits(v) + 0x8000u) >> 16);
}
static __device__ __forceinline__ unsigned pack2(float a, float b) {
    return __builtin_amdgcn_perm(fbits(b) + 0x8000u, fbits(a) + 0x8000u, 0x07060302u);
}
static __device__ __forceinline__ s16x8 load_frag(const void* p) {
    u32x4a t = *(const u32x4a*)p;
    return __builtin_bit_cast(s16x8, t);
}

#define SQC1 0.4246609177f  // sqrt(log2(e)/8), applied to kt on both Q and K sides

// grid (TT/64, NB, 2), 256 threads. Reads c-major f32, emits frag-packed bf16.
__global__ void prep_k(const float* __restrict__ x1, const float* __restrict__ x2,
                       ushort* __restrict__ kt, ushort* __restrict__ vt) {
    const int inp = blockIdx.z, b = blockIdx.y, tt = blockIdx.x;
    const float* src = (inp == 0 ? x1 : x2) + (size_t)b * CC * TT;
    const size_t plane = (size_t)TT * CC;
    ushort* kd = kt + (size_t)(inp * NB + b) * plane;
    ushort* vd = vt + (size_t)(inp * NB + b) * plane;
    __shared__ ushort lds[64][72];
    const int tid = threadIdx.x;
    const int c  = tid >> 2;        // 0..63: channel row
    const int tg = tid & 3;         // 16-token group within the 64-token tile
    const float* srow = src + (size_t)c * TT + tt * 64 + tg * 16;
    unsigned hw[8];
#pragma unroll
    for (int i = 0; i < 4; ++i) {
        f32x4a v = *(const f32x4a*)(srow + i * 4);
        hw[2 * i]     = pack2(v[0], v[1]);
        hw[2 * i + 1] = pack2(v[2], v[3]);
#pragma unroll
        for (int k = 0; k < 4; ++k) lds[tg * 16 + i * 4 + k][c] = bf16of(v[k] * SQC1);
    }
    // vt frag-packed (unscaled): thread(c,tg) owns V[c][t_local=tg*16..+16] =
    // chunk(tt, ch2=tg>>1, ct=c>>4), lanes (quad=(tg&1)*2 and +1, l16=c&15).
    {
        ushort* vchunk = vd + (((size_t)tt * 2 + (tg >> 1)) * 4 + (c >> 4)) * 512;
        const int l16v = c & 15;
        const int q0v  = (tg & 1) * 2;
        u32x4a w0 = {hw[0], hw[1], hw[2], hw[3]};
        u32x4a w1 = {hw[4], hw[5], hw[6], hw[7]};
        *(u32x4a*)(vchunk + (size_t)(q0v * 16 + l16v) * 8)       = w0;
        *(u32x4a*)(vchunk + (size_t)((q0v + 1) * 16 + l16v) * 8) = w1;
    }
    __syncthreads();
    // kt frag-packed (scaled, from transposed LDS): tid = mt*64 + quad*16 + l16.
    // chunk(tt, mt, ch): lane holds 8 consecutive c at row t = mt*16 + l16.
    const int mt   = tid >> 6;
    const int quad = (tid >> 4) & 3;
    const int l16  = tid & 15;
    const int t    = mt * 16 + l16;
#pragma unroll
    for (int ch = 0; ch < 2; ++ch) {
        u32x4a w = *(const u32x4a*)&lds[t][ch * 32 + quad * 8];
        *(u32x4a*)(kd + (((size_t)tt * 4 + mt) * 2 + ch) * 512 +
                   (size_t)(quad * 16 + l16) * 8) = w;
    }
}

// grid = 512 blocks (qt 0..63 x b 0..7), 512 threads = 8 waves.
// wave: dir = w&1, pair = (w>>1)&1, ks = w>>2 (2048-token half).
// (512,1): min-waves 1 -> VGPR budget 256; residency floor is 1 block anyway.
__global__ __launch_bounds__(512, 1)
void attn_fused_k(const ushort* __restrict__ kt, const ushort* __restrict__ vt,
                  float* __restrict__ out) {
    const int b    = blockIdx.x & 7;
    const int qt   = blockIdx.x >> 3;
    const int tid  = threadIdx.x;
    const int wave = tid >> 6;
    const int lane = tid & 63;
    const int quad = lane >> 4;
    const int l16  = lane & 15;
    const int dir  = wave & 1;
    const int pair = (wave >> 1) & 1;
    const int ks   = wave >> 2;
    const int q0   = qt * 64 + pair * 32;

    const size_t plane = (size_t)TT * CC;
    // All hot-loop loads: base + chunk*512 + lane*8 (ushorts) = contiguous 1KB/instr.
    const ushort* Qp = kt + (size_t)((dir == 0 ? 0 : NB) + b) * plane + (size_t)lane * 8;
    const ushort* Kp = kt + (size_t)((dir == 0 ? NB : 0) + b) * plane + (size_t)lane * 8;
    const ushort* Vp = vt + (size_t)((dir == 0 ? NB : 0) + b) * plane + (size_t)lane * 8;

    // pbuf[wave][par][rb][q=16][tok 64 + pad]: parity-split so S(j+1) writes and
    // PV(j) reads touch different regions -> DS queue no longer serializes them.
    __shared__ __align__(16) ushort pbuf[8][2][2][16][72];  // 72 KB
    __shared__ float lpx[8][2][16];                         // 1 KB
    f32a* xbuf = (f32a*)&pbuf[0][0][0][0][0];               // 16 KB overlay, post-loop

    // Q b-frags = kt chunks (qt, mt = pair*2 + rb, ch), pre-scaled.
    s16x8 qf[2][2];
#pragma unroll
    for (int rb = 0; rb < 2; ++rb)
#pragma unroll
        for (int ch = 0; ch < 2; ++ch)
            qf[rb][ch] = load_frag(Qp + (((size_t)qt * 4 + pair * 2 + rb) * 2 + ch) * 512);

    f32x4 accO[2][4];  // O^T partial: row=c=quad*4+r (+ct*16), col=q=l16 (+rb*16)
#pragma unroll
    for (int rb = 0; rb < 2; ++rb)
#pragma unroll
        for (int ct = 0; ct < 4; ++ct) accO[rb][ct] = (f32x4){0.f, 0.f, 0.f, 0.f};
    float lp[2] = {0.f, 0.f};

    // Named registers only (R14/R15 lesson: arrays spill under pressure).
    s16x8 kA0, kA1, kA2, kA3, kA4, kA5, kA6, kA7;   // K set A (even j)
    s16x8 kB0, kB1, kB2, kB3, kB4, kB5, kB6, kB7;   // K set B (odd j)
    s16x8 vA0, vA1, vA2, vA3, vA4, vA5, vA6, vA7;   // V set A (even j)
    s16x8 vB0, vB1, vB2, vB3, vB4, vB5, vB6, vB7;   // V set B (odd j)

    auto loadKA = [&](int j) {
        const ushort* p = Kp + (size_t)(ks * 32 + j) * 4096;
        kA0 = load_frag(p);          kA1 = load_frag(p + 512);
        kA2 = load_frag(p + 1024);   kA3 = load_frag(p + 1536);
        kA4 = load_frag(p + 2048);   kA5 = load_frag(p + 2560);
        kA6 = load_frag(p + 3072);   kA7 = load_frag(p + 3584);
    };
    auto loadKB = [&](int j) {
        const ushort* p = Kp + (size_t)(ks * 32 + j) * 4096;
        kB0 = load_frag(p);          kB1 = load_frag(p + 512);
        kB2 = load_frag(p + 1024);   kB3 = load_frag(p + 1536);
        kB4 = load_frag(p + 2048);   kB5 = load_frag(p + 2560);
        kB6 = load_frag(p + 3072);   kB7 = load_frag(p + 3584);
    };
    auto loadVA = [&](int j) {
        const ushort* p = Vp + (size_t)(ks * 32 + j) * 4096;
        vA0 = load_frag(p);          vA1 = load_frag(p + 512);
        vA2 = load_frag(p + 1024);   vA3 = load_frag(p + 1536);
        vA4 = load_frag(p + 2048);   vA5 = load_frag(p + 2560);
        vA6 = load_frag(p + 3072);   vA7 = load_frag(p + 3584);
    };
    auto loadVB = [&](int j) {
        const ushort* p = Vp + (size_t)(ks * 32 + j) * 4096;
        vB0 = load_frag(p);          vB1 = load_frag(p + 512);
        vB2 = load_frag(p + 1024);   vB3 = load_frag(p + 1536);
        vB4 = load_frag(p + 2048);   vB5 = load_frag(p + 2560);
        vB6 = load_frag(p + 3072);   vB7 = load_frag(p + 3584);
    };

    // One mt-slice of S^T into parity region par:
    // D[row=tok=quad*4+r (+mt*16)][col=q=l16] -> b64 P write.
    auto SmT = [&](s16x8 kc0, s16x8 kc1, int mt, int par) {
#pragma unroll
        for (int rb = 0; rb < 2; ++rb) {
            f32x4 s = (f32x4){0.f, 0.f, 0.f, 0.f};
            s = __builtin_amdgcn_mfma_f32_16x16x32_bf16(kc0, qf[rb][0], s, 0, 0, 0);
            s = __builtin_amdgcn_mfma_f32_16x16x32_bf16(kc1, qf[rb][1], s, 0, 0, 0);
            float p0 = __builtin_amdgcn_exp2f(s[0]);
            float p1 = __builtin_amdgcn_exp2f(s[1]);
            float p2 = __builtin_amdgcn_exp2f(s[2]);
            float p3 = __builtin_amdgcn_exp2f(s[3]);
            lp[rb] += (p0 + p1) + (p2 + p3);
            u32x2a w;
            w[0] = pack2(p0, p1);
            w[1] = pack2(p2, p3);
            *(u32x2a*)&pbuf[wave][par][rb][l16][mt * 16 + quad * 4] = w;
        }
    };
    // PV from parity region par with V set A (even j) / B (odd j).
    auto PVA = [&]() {
        s16x8 pf0a = load_frag(&pbuf[wave][0][0][l16][quad * 8]);
        s16x8 pf1a = load_frag(&pbuf[wave][0][1][l16][quad * 8]);
        accO[0][0] = __builtin_amdgcn_mfma_f32_16x16x32_bf16(vA0, pf0a, accO[0][0], 0, 0, 0);
        accO[1][0] = __builtin_amdgcn_mfma_f32_16x16x32_bf16(vA0, pf1a, accO[1][0], 0, 0, 0);
        accO[0][1] = __builtin_amdgcn_mfma_f32_16x16x32_bf16(vA1, pf0a, accO[0][1], 0, 0, 0);
        accO[1][1] = __builtin_amdgcn_mfma_f32_16x16x32_bf16(vA1, pf1a, accO[1][1], 0, 0, 0);
        accO[0][2] = __builtin_amdgcn_mfma_f32_16x16x32_bf16(vA2, pf0a, accO[0][2], 0, 0, 0);
        accO[1][2] = __builtin_amdgcn_mfma_f32_16x16x32_bf16(vA2, pf1a, accO[1][2], 0, 0, 0);
        accO[0][3] = __builtin_amdgcn_mfma_f32_16x16x32_bf16(vA3, pf0a, accO[0][3], 0, 0, 0);
        accO[1][3] = __builtin_amdgcn_mfma_f32_16x16x32_bf16(vA3, pf1a, accO[1][3], 0, 0, 0);
        s16x8 pf0b = load_frag(&pbuf[wave][0][0][l16][32 + quad * 8]);
        s16x8 pf1b = load_frag(&pbuf[wave][0][1][l16][32 + quad * 8]);
        accO[0][0] = __builtin_amdgcn_mfma_f32_16x16x32_bf16(vA4, pf0b, accO[0][0], 0, 0, 0);
        accO[1][0] = __builtin_amdgcn_mfma_f32_16x16x32_bf16(vA4, pf1b, accO[1][0], 0, 0, 0);
        accO[0][1] = __builtin_amdgcn_mfma_f32_16x16x32_bf16(vA5, pf0b, accO[0][1], 0, 0, 0);
        accO[1][1] = __builtin_amdgcn_mfma_f32_16x16x32_bf16(vA5, pf1b, accO[1][1], 0, 0, 0);
        accO[0][2] = __builtin_amdgcn_mfma_f32_16x16x32_bf16(vA6, pf0b, accO[0][2], 0, 0, 0);
        accO[1][2] = __builtin_amdgcn_mfma_f32_16x16x32_bf16(vA6, pf1b, accO[1][2], 0, 0, 0);
        accO[0][3] = __builtin_amdgcn_mfma_f32_16x16x32_bf16(vA7, pf0b, accO[0][3], 0, 0, 0);
        accO[1][3] = __builtin_amdgcn_mfma_f32_16x16x32_bf16(vA7, pf1b, accO[1][3], 0, 0, 0);
    };
    auto PVB = [&]() {
        s16x8 pf0a = load_frag(&pbuf[wave][1][0][l16][quad * 8]);
        s16x8 pf1a = load_frag(&pbuf[wave][1][1][l16][quad * 8]);
        accO[0][0] = __builtin_amdgcn_mfma_f32_16x16x32_bf16(vB0, pf0a, accO[0][0], 0, 0, 0);
        accO[1][0] = __builtin_amdgcn_mfma_f32_16x16x32_bf16(vB0, pf1a, accO[1][0], 0, 0, 0);
        accO[0][1] = __builtin_amdgcn_mfma_f32_16x16x32_bf16(vB1, pf0a, accO[0][1], 0, 0, 0);
        accO[1][1] = __builtin_amdgcn_mfma_f32_16x16x32_bf16(vB1, pf1a, accO[1][1], 0, 0, 0);
        accO[0][2] = __builtin_amdgcn_mfma_f32_16x16x32_bf16(vB2, pf0a, accO[0][2], 0, 0, 0);
        accO[1][2] = __builtin_amdgcn_mfma_f32_16x16x32_bf16(vB2, pf1a, accO[1][2], 0, 0, 0);
        accO[0][3] = __builtin_amdgcn_mfma_f32_16x16x32_bf16(vB3, pf0a, accO[0][3], 0, 0, 0);
        accO[1][3] = __builtin_amdgcn_mfma_f32_16x16x32_bf16(vB3, pf1a, accO[1][3], 0, 0, 0);
        s16x8 pf0b = load_frag(&pbuf[wave][1][0][l16][32 + quad * 8]);
        s16x8 pf1b = load_frag(&pbuf[wave][1][1][l16][32 + quad * 8]);
        accO[0][0] = __builtin_amdgcn_mfma_f32_16x16x32_bf16(vB4, pf0b, accO[0][0], 0, 0, 0);
        accO[1][0] = __builtin_amdgcn_mfma_f32_16x16x32_bf16(vB4, pf1b, accO[1][0], 0, 0, 0);
        accO[0][1] = __builtin_amdgcn_mfma_f32_16x16x32_bf16(vB5, pf0b, accO[0][1], 0, 0, 0);
        accO[1][1] = __builtin_amdgcn_mfma_f32_16x16x32_bf16(vB5, pf1b, accO[1][1], 0, 0, 0);
        accO[0][2] = __builtin_amdgcn_mfma_f32_16x16x32_bf16(vB6, pf0b, accO[0][2], 0, 0, 0);
        accO[1][2] = __builtin_amdgcn_mfma_f32_16x16x32_bf16(vB6, pf1b, accO[1][2], 0, 0, 0);
        accO[0][3] = __builtin_amdgcn_mfma_f32_16x16x32_bf16(vB7, pf0b, accO[0][3], 0, 0, 0);
        accO[1][3] = __builtin_amdgcn_mfma_f32_16x16x32_bf16(vB7, pf1b, accO[1][3], 0, 0, 0);
    };

    // Barrier-free parity pipeline, unroll 2. Per iter (j even):
    //   loadKB(j+1) -> S(kA)->par0 -> loadVB(j+1) -> S(kB)->par1 [indep of PV]
    //   -> loadKA(j+2) -> PV(j){vA,par0: written 1 phase ago} -> loadVA(j+2)
    //   -> PV(j+1){vB,par1}.
    // Every consumer's input is >=1 full phase old; the DS in-order queue no
    // longer chains S(j+1) writes behind PV(j) reads (different parity region).
    loadKA(0);
    loadVA(0);
#pragma unroll 1
    for (int j = 0; j < 32; j += 2) {
        loadKB(j + 1);
        SmT(kA0, kA1, 0, 0); SmT(kA2, kA3, 1, 0); SmT(kA4, kA5, 2, 0); SmT(kA6, kA7, 3, 0);
        loadVB(j + 1);
        SmT(kB0, kB1, 0, 1); SmT(kB2, kB3, 1, 1); SmT(kB4, kB5, 2, 1); SmT(kB6, kB7, 3, 1);
        if (j + 2 < 32) loadKA(j + 2);
        PVA();                           // PV(j)
        if (j + 2 < 32) loadVA(j + 2);
        PVB();                           // PV(j+1)
    }

    // Denominator: quads hold disjoint token subsets for col q=l16.
    float inv[2];
#pragma unroll
    for (int rb = 0; rb < 2; ++rb) {
        float l = lp[rb];
        l += __shfl_xor(l, 16);
        l += __shfl_xor(l, 32);
        lp[rb] = l;
        if (lane < 16) lpx[wave][rb][l16] = l;
    }
    __syncthreads();  // joins ALL waves after their last pbuf use ->
                      // xbuf overlay safe; lpx visible
#pragma unroll
    for (int rb = 0; rb < 2; ++rb)
        inv[rb] = __builtin_amdgcn_rcpf(lp[rb] + lpx[wave ^ 4][rb][l16]);

    // 4-phase merge over g = (ks,dir) into xbuf[pair]; g==0 stores.
    const int g = (ks << 1) | dir;
#pragma unroll 1
    for (int ph = 3; ph >= 1; --ph) {
        if (g == ph) {
#pragma unroll
            for (int rb = 0; rb < 2; ++rb)
#pragma unroll
                for (int ct = 0; ct < 4; ++ct)
#pragma unroll
                    for (int r = 0; r < 4; ++r) {
                        const int slot = (pair * 32 + rb * 16 + ct * 4 + r) * 64 + lane;
                        float v = accO[rb][ct][r] * inv[rb];
                        if (ph == 3) xbuf[slot] = v;
                        else xbuf[slot] += v;
                    }
        }
        __syncthreads();
    }
    if (g == 0) {
        float* ob = out + (size_t)b * plane;
#pragma unroll
        for (int rb = 0; rb < 2; ++rb)
#pragma unroll
            for (int ct = 0; ct < 4; ++ct)
#pragma unroll
                for (int r = 0; r < 4; ++r) {
                    float v = accO[rb][ct][r] * inv[rb] +
                              xbuf[(pair * 32 + rb * 16 + ct * 4 + r) * 64 + lane];
                    // out[c = ct*16+quad*4+r][t = q0+rb*16+l16]: coalesced over l16
                    ob[(size_t)(ct * 16 + quad * 4 + r) * TT + q0 + rb * 16 + l16] = v;
                }
    }
}

extern "C" void kernel_launch(void* const* d_in, const int* in_sizes, int n_in,
                              void* d_out, int out_size, void* d_ws, size_t ws_size,
                              hipStream_t stream) {
    const float* x1 = (const float*)d_in[0];
    const float* x2 = (const float*)d_in[1];
    ushort* kt = (ushort*)d_ws;                              // 8 MB frag-packed K/Q
    ushort* vt = (ushort*)d_ws + (size_t)2 * NB * TT * CC;   // 8 MB frag-packed V

    hipLaunchKernelGGL(prep_k, dim3(TT / 64, NB, 2), dim3(256), 0, stream, x1, x2, kt, vt);
    hipLaunchKernelGGL(attn_fused_k, dim3(64 * NB), dim3(512), 0, stream,
                       kt, vt, (float*)d_out);
}